// Round 4
// baseline (183.583 us; speedup 1.0000x reference)
//
#include <hip/hip_runtime.h>
#include <hip/hip_bf16.h>
#include <utility>

// out[131072,18] = theta(x)[131072,1330] @ (xi*mask)[1330,18]
// bf16 MFMA GEMM via mfma_f32_16x16x32_bf16.
// Order-4 symmetry rho = (0123)(4567)(89AB)(CDEF)(16 17): 1330 monomials ->
// 342 rep slots -> 43 K-chunks of 32. Lane-quad g evaluates the same
// compile-time rep expressions on rho^g-permuted inputs.
// Round-10 structure:
//  - DESIGN TO THE 64-VGPR BUDGET. Rounds 2/3 proved the allocator targets
//    64 VGPRs for this 512-thread kernel no matter what (waves_per_eu(4,4)
//    + LDS pad both ignored), and the 2-row-packed structure (x as f32x2[18]
//    = 36 regs) then spills ~33 regs -> 34 MB of scratch traffic (WRITE_SIZE
//    44 MB vs 9.4 MB output) and a 144 us cold dispatch (lazy scratch alloc).
//    Fix: each wave's 32 rows are processed in TWO SEQUENTIAL PASSES of 16
//    rows (runtime npass arg so the loop can't unroll). Per-pass live set
//    ~50 regs -> zero spills. LDS B-frag reads double (~2.8 MB/CU, ~12 us
//    pipe time, overlapped) - far cheaper than scratch.
//  - W table stays in module-scope g_wf (prep dispatch + linear float4 LDS
//    staging). The harness's 256 MiB workspace poison fill is UNCONDITIONAL
//    (present even in the zero-workspace round 2), so ~45 us of dur_us is
//    harness floor; minimizing vindy itself is all that's left.

constexpr int NVARS   = 18;
constexpr int NOUT    = 18;
constexpr int NROWS   = 131072;
constexpr int NCHUNKS = 43;             // K = 43*32 = 1376
constexpr int NSLOTS  = NCHUNKS * 8;    // 344 (342 used + 2 pad)

constexpr int WF0_SHORTS = NCHUNKS * 512;   // tile0 frags: 22016 shorts (44032 B)
constexpr int WF1_SHORTS = NCHUNKS * 72;    // compact tile1 + zero slot: 3096 shorts
constexpr int WF_SHORTS  = WF0_SHORTS + WF1_SHORTS;  // 25112 shorts = 50224 B

typedef __attribute__((ext_vector_type(8))) short short8;
typedef __attribute__((ext_vector_type(4))) float f32x4;

struct T3 { int a, b, c; };   // sorted ascending; 18 = unused factor; 19 = pad

constexpr int rho1(int v) {
    if (v < 16)  return (v & ~3) | ((v + 1) & 3);
    if (v == 16) return 17;
    if (v == 17) return 16;
    return v;
}
constexpr int rho2v(int v) { return rho1(rho1(v)); }

constexpr T3 sort3(int u0, int u1, int u2) {
    int t = 0;
    if (u0 > u1) { t = u0; u0 = u1; u1 = t; }
    if (u1 > u2) { t = u1; u1 = u2; u2 = t; }
    if (u0 > u1) { t = u0; u0 = u1; u1 = t; }
    return T3{u0, u1, u2};
}
constexpr T3 rho3(T3 t) { return sort3(rho1(t.a), rho1(t.b), rho1(t.c)); }

constexpr bool t3_less(T3 x, T3 y) {
    if (x.a != y.a) return x.a < y.a;
    if (x.b != y.b) return x.b < y.b;
    return x.c < y.c;
}
constexpr bool t3_eq(T3 x, T3 y) { return x.a == y.a && x.b == y.b && x.c == y.c; }

constexpr int rank_of(T3 t) {
    int deg = (t.a < 18) + (t.b < 18) + (t.c < 18);
    if (deg == 0) return 0;
    if (deg == 1) return 1 + t.a;
    if (deg == 2) {
        int r = 19;
        for (int a = 0; a < t.a; ++a) r += 18 - a;
        return r + (t.b - t.a);
    }
    int r = 190;
    for (int a = 0; a < t.a; ++a) { int n = 18 - a; r += n * (n + 1) / 2; }
    for (int b = t.a; b < t.b; ++b) r += 18 - b;
    return r + (t.c - t.b);
}

struct RepTables {
    signed char va[NSLOTS], vb[NSLOTS], vc[NSLOTS];
    short p[4][NSLOTS];   // flat term index for group g's k-position; -1 => zero W
    int count;
};

constexpr void consider(RepTables& R, int& s, T3 t) {
    T3 im[4] = {t, T3{0, 0, 0}, T3{0, 0, 0}, T3{0, 0, 0}};
    im[1] = rho3(im[0]);
    im[2] = rho3(im[1]);
    im[3] = rho3(im[2]);
    for (int g = 1; g < 4; ++g)
        if (t3_less(im[g], t)) return;   // not the orbit representative
    R.va[s] = (signed char)t.a; R.vb[s] = (signed char)t.b; R.vc[s] = (signed char)t.c;
    for (int g = 0; g < 4; ++g) {
        bool dup = false;
        for (int h = 0; h < g; ++h)
            if (t3_eq(im[h], im[g])) dup = true;
        R.p[g][s] = dup ? (short)-1 : (short)rank_of(im[g]);
    }
    ++s;
}

constexpr RepTables make_tables() {
    RepTables R{};
    int s = 0;
    consider(R, s, T3{18, 18, 18});
    for (int a = 0; a < NVARS; ++a) consider(R, s, T3{a, 18, 18});
    for (int a = 0; a < NVARS; ++a)
        for (int b = a; b < NVARS; ++b) consider(R, s, T3{a, b, 18});
    for (int a = 0; a < NVARS; ++a)
        for (int b = a; b < NVARS; ++b)
            for (int c = b; c < NVARS; ++c) consider(R, s, T3{a, b, c});
    R.count = s;
    for (; s < NSLOTS; ++s) {
        R.va[s] = 19; R.vb[s] = 19; R.vc[s] = 19;
        for (int g = 0; g < 4; ++g) R.p[g][s] = -1;
    }
    return R;
}

constexpr RepTables h_tab = make_tables();          // compile-time use
static_assert(h_tab.count == 342, "orbit enumeration must give 342 rep slots");
__device__ const RepTables d_tab = make_tables();   // runtime use (prep)

// Module-scope staging buffer for the prepped W table (NOT harness workspace).
__device__ __align__(16) short g_wf[WF_SHORTS];

// ---- bf16 pair pack --------------------------------------------------------

#if __has_builtin(__builtin_amdgcn_cvt_pk_bf16_f32)
typedef __bf16 bf16x2 __attribute__((ext_vector_type(2)));
__device__ __forceinline__ unsigned pack2(float f0, float f1) {
    bf16x2 r = __builtin_amdgcn_cvt_pk_bf16_f32(f0, f1);   // lo=f0, hi=f1, RNE
    return __builtin_bit_cast(unsigned, r);
}
#else
__device__ __forceinline__ unsigned pack2(float f0, float f1) {
    unsigned u0 = __float_as_uint(f0) + 0x8000u;
    unsigned u1 = __float_as_uint(f1) + 0x8000u;
    return __builtin_amdgcn_perm(u1, u0, 0x07060302u);     // lo=bf16(f0), hi=bf16(f1)
}
#endif

// ---- main kernel -----------------------------------------------------------

template <int S>
__device__ __forceinline__ float term_val(const float (&x)[NVARS]) {
    constexpr int a = h_tab.va[S], b = h_tab.vb[S], c = h_tab.vc[S];
    if constexpr (a >= 19)      return 0.0f;                 // pad slot
    else if constexpr (a == 18) return 1.0f;                 // constant
    else if constexpr (b == 18) return x[a];
    else if constexpr (c == 18) return x[a] * x[b];
    else                        return x[a] * x[b] * x[c];
}

union AFrag { unsigned u[4]; short8 v; };

template <int CI, int... I>
__device__ __forceinline__ void eval8(const float (&x)[NVARS], float (&t)[8],
                                      std::integer_sequence<int, I...>) {
    ((t[I] = term_val<CI * 8 + I>(x)), ...);
}

template <int CI>
__device__ __forceinline__ void kstep(const float (&x)[NVARS],
                                      const short* p0, const short* p1,
                                      f32x4& acc0, f32x4& acc1) {
    float t[8];
    eval8<CI>(x, t, std::make_integer_sequence<int, 8>{});
    AFrag af;
#pragma unroll
    for (int j = 0; j < 4; ++j) af.u[j] = pack2(t[2 * j], t[2 * j + 1]);
    short8 b0 = *(const short8*)(p0 + CI * 512);   // tile0 frag, ds_read_b128
    short8 b1 = *(const short8*)(p1 + CI * 72);    // compact tile1 frag (zero slot for n>=2)
    acc0 = __builtin_amdgcn_mfma_f32_16x16x32_bf16(af.v, b0, acc0, 0, 0, 0);
    acc1 = __builtin_amdgcn_mfma_f32_16x16x32_bf16(af.v, b1, acc1, 0, 0, 0);
}

template <int... CI>
__device__ __forceinline__ void kloop(const float (&x)[NVARS],
                                      const short* p0, const short* p1,
                                      f32x4& acc0, f32x4& acc1,
                                      std::integer_sequence<int, CI...>) {
    (kstep<CI>(x, p0, p1, acc0, acc1), ...);
}

__device__ __forceinline__ void load_x(const float* __restrict__ z,
                                       const float* __restrict__ betas,
                                       int arow, bool s1, bool s2, float (&x)[NVARS]) {
    float x0[NVARS];
    const float4* z4 = (const float4*)(z + (size_t)arow * 16);
    float4 v0 = z4[0], v1 = z4[1], v2 = z4[2], v3 = z4[3];
    x0[0]  = v0.x; x0[1]  = v0.y; x0[2]  = v0.z; x0[3]  = v0.w;
    x0[4]  = v1.x; x0[5]  = v1.y; x0[6]  = v1.z; x0[7]  = v1.w;
    x0[8]  = v2.x; x0[9]  = v2.y; x0[10] = v2.z; x0[11] = v2.w;
    x0[12] = v3.x; x0[13] = v3.y; x0[14] = v3.z; x0[15] = v3.w;
    const float2 b2 = *(const float2*)(betas + (size_t)arow * 2);
    x0[16] = b2.x; x0[17] = b2.y;
    float y[NVARS];
#pragma unroll
    for (int v = 0; v < NVARS; ++v) y[v] = s1 ? x0[rho1(v)] : x0[v];
#pragma unroll
    for (int v = 0; v < NVARS; ++v) x[v] = s2 ? y[rho2v(v)] : y[v];
}

__global__ __launch_bounds__(512) void vindy_mfma(const float* __restrict__ z,
                                                  const float* __restrict__ betas,
                                                  float* __restrict__ out,
                                                  int npass) {
    __shared__ __align__(16) short ldsW[WF_SHORTS];   // 50224 B

    // stage all W fragments once per block (flat 16B copies, fully coalesced)
    {
        const float4* src = (const float4*)g_wf;
        float4* dst = (float4*)ldsW;
        for (int i = threadIdx.x; i < WF_SHORTS / 8; i += 512) dst[i] = src[i];
    }
    __syncthreads();

    const int lane = threadIdx.x & 63;
    const int wave = threadIdx.x >> 6;   // 0..7
    const int g    = lane >> 4;          // rho-power / k-quad
    const int n    = lane & 15;          // A-row within tile; C col
    const int rowbase = blockIdx.x * 256 + wave * 32;

    const bool s1 = (g & 1) != 0;
    const bool s2 = (g & 2) != 0;

    const short* p0 = ldsW + lane * 8;                                    // tile0 base
    const short* p1 = ldsW + WF0_SHORTS + (n < 2 ? (g * 2 + n) * 8 : 64); // tile1 / zero slot

    // Two passes of 16 rows. npass is a RUNTIME arg (always 2) so the loop
    // cannot unroll: only one x[18] is ever live -> ~50 live VGPRs, no spill
    // at the allocator's 64-reg target (rounds 2/3 failure mode).
    for (int half = 0; half < npass; ++half) {
        const int row0 = rowbase + half * 16;
        float x[NVARS];
        load_x(z, betas, row0 + n, s1, s2, x);

        f32x4 acc0, acc1;
#pragma unroll
        for (int i = 0; i < 4; ++i) { acc0[i] = 0.0f; acc1[i] = 0.0f; }

        kloop(x, p0, p1, acc0, acc1, std::make_integer_sequence<int, NCHUNKS>{});

        // C/D 16x16 layout: col = lane&15, row = g*4 + reg
        float* o = out + (size_t)(row0 + g * 4) * NOUT;
#pragma unroll
        for (int r = 0; r < 4; ++r) o[(size_t)r * NOUT + n] = acc0[r];
        if (n < 2) {
#pragma unroll
            for (int r = 0; r < 4; ++r) o[(size_t)r * NOUT + 16 + n] = acc1[r];
        }
    }
}

// ---- prep: W fragments in staged layout ------------------------------------
// region 0 (tile0, cols 0-15): wf[c*512 + l*8 + j] = W[p[l>>4][c*8+j]][l&15]
// region 1 (tile1 compact, 72 shorts/chunk):
//   q = 0..7:  wf[WF0 + c*72 + q*8 + j] = W[p[q>>1][c*8+j]][16+(q&1)]
//   q = 8:     zero slot (read by lanes n>=2)

__global__ void prep_wfrag(const float* __restrict__ xi, const float* __restrict__ mask) {
    int i = blockIdx.x * blockDim.x + threadIdx.x;
    if (i >= WF_SHORTS) return;
    float v = 0.0f;
    if (i < WF0_SHORTS) {
        int j = i & 7, l = (i >> 3) & 63, c = i >> 9;
        int col = l & 15;
        int p = d_tab.p[l >> 4][c * 8 + j];
        if (p >= 0) v = xi[p * NOUT + col] * mask[p * NOUT + col];
    } else {
        int i2 = i - WF0_SHORTS;
        int c = i2 / 72;
        int r = i2 - c * 72;
        int q = r >> 3, j = r & 7;
        if (q < 8) {
            int col = 16 + (q & 1);
            int p = d_tab.p[q >> 1][c * 8 + j];
            if (p >= 0) v = xi[p * NOUT + col] * mask[p * NOUT + col];
        }
    }
    g_wf[i] = __builtin_bit_cast(short, __float2bfloat16(v));
}

extern "C" void kernel_launch(void* const* d_in, const int* in_sizes, int n_in,
                              void* d_out, int out_size, void* d_ws, size_t ws_size,
                              hipStream_t stream) {
    const float* z     = (const float*)d_in[0];
    const float* betas = (const float*)d_in[1];
    const float* xi    = (const float*)d_in[2];
    const float* mask  = (const float*)d_in[3];
    float* out = (float*)d_out;
    (void)d_ws; (void)ws_size;   // workspace unused (poison fill is unconditional anyway)

    prep_wfrag<<<(WF_SHORTS + 255) / 256, 256, 0, stream>>>(xi, mask);
    vindy_mfma<<<NROWS / 256, 512, 0, stream>>>(z, betas, out, 2);
}

// Round 5
// 104.121 us; speedup vs baseline: 1.7632x; 1.7632x over previous
//
#include <hip/hip_runtime.h>
#include <hip/hip_bf16.h>
#include <utility>

// out[131072,18] = theta(x)[131072,1330] @ (xi*mask)[1330,18]
// bf16 MFMA GEMM via mfma_f32_16x16x32_bf16.
// Order-4 symmetry rho = (0123)(4567)(89AB)(CDEF)(16 17): 1330 monomials ->
// 342 rep slots -> 43 K-chunks of 32. Lane-quad g evaluates the same
// compile-time rep expressions on rho^g-permuted inputs.
// Round-11 structure: round-0 BODY (the only spill-free structure across 5
// rounds: dual 16-row tiles per wave, scalar float x[18] pairs, explicit
// launch_bounds 2nd arg), with fixed dispatch geometry:
//  - 1024-thread blocks (16 waves x 32 rows = 512 rows), grid = 256
//    = EXACTLY 1 block/CU -> zero tail (round 0 ran 1024 blocks over a
//    768-block capacity = 1.33 rounds) and 4 waves/SIMD (was 3).
//  - LDS padded to 82,944 B so 2 blocks/CU physically cannot fit
//    (2x82944 > 163840): the only achievable occupancy is 4 waves/EU, so
//    the allocator's budget is 128 VGPRs. Rounds 2-4 proved that any
//    geometry where more waves are theoretically reachable makes the
//    allocator target 64 VGPRs and spill (44-212 MB of scratch traffic).
//  - W table in module-scope g_wf; prep dispatch + linear float4 staging.
//    The harness's 256 MiB workspace poison fill is UNCONDITIONAL (~45 us
//    floor), aux/gaps ~12 us; vindy itself is the only remaining lever.

constexpr int NVARS   = 18;
constexpr int NOUT    = 18;
constexpr int NROWS   = 131072;
constexpr int NCHUNKS = 43;             // K = 43*32 = 1376
constexpr int NSLOTS  = NCHUNKS * 8;    // 344 (342 used + 2 pad)

constexpr int WF0_SHORTS = NCHUNKS * 512;   // tile0 frags: 22016 shorts (44032 B)
constexpr int WF1_SHORTS = NCHUNKS * 72;    // compact tile1 + zero slot: 3096 shorts
constexpr int WF_SHORTS  = WF0_SHORTS + WF1_SHORTS;  // 25112 shorts = 50224 B
constexpr int LDS_SHORTS = 41472;           // 82944 B: 2 blocks/CU impossible

typedef __attribute__((ext_vector_type(8))) short short8;
typedef __attribute__((ext_vector_type(4))) float f32x4;

struct T3 { int a, b, c; };   // sorted ascending; 18 = unused factor; 19 = pad

constexpr int rho1(int v) {
    if (v < 16)  return (v & ~3) | ((v + 1) & 3);
    if (v == 16) return 17;
    if (v == 17) return 16;
    return v;
}
constexpr int rho2v(int v) { return rho1(rho1(v)); }

constexpr T3 sort3(int u0, int u1, int u2) {
    int t = 0;
    if (u0 > u1) { t = u0; u0 = u1; u1 = t; }
    if (u1 > u2) { t = u1; u1 = u2; u2 = t; }
    if (u0 > u1) { t = u0; u0 = u1; u1 = t; }
    return T3{u0, u1, u2};
}
constexpr T3 rho3(T3 t) { return sort3(rho1(t.a), rho1(t.b), rho1(t.c)); }

constexpr bool t3_less(T3 x, T3 y) {
    if (x.a != y.a) return x.a < y.a;
    if (x.b != y.b) return x.b < y.b;
    return x.c < y.c;
}
constexpr bool t3_eq(T3 x, T3 y) { return x.a == y.a && x.b == y.b && x.c == y.c; }

constexpr int rank_of(T3 t) {
    int deg = (t.a < 18) + (t.b < 18) + (t.c < 18);
    if (deg == 0) return 0;
    if (deg == 1) return 1 + t.a;
    if (deg == 2) {
        int r = 19;
        for (int a = 0; a < t.a; ++a) r += 18 - a;
        return r + (t.b - t.a);
    }
    int r = 190;
    for (int a = 0; a < t.a; ++a) { int n = 18 - a; r += n * (n + 1) / 2; }
    for (int b = t.a; b < t.b; ++b) r += 18 - b;
    return r + (t.c - t.b);
}

struct RepTables {
    signed char va[NSLOTS], vb[NSLOTS], vc[NSLOTS];
    short p[4][NSLOTS];   // flat term index for group g's k-position; -1 => zero W
    int count;
};

constexpr void consider(RepTables& R, int& s, T3 t) {
    T3 im[4] = {t, T3{0, 0, 0}, T3{0, 0, 0}, T3{0, 0, 0}};
    im[1] = rho3(im[0]);
    im[2] = rho3(im[1]);
    im[3] = rho3(im[2]);
    for (int g = 1; g < 4; ++g)
        if (t3_less(im[g], t)) return;   // not the orbit representative
    R.va[s] = (signed char)t.a; R.vb[s] = (signed char)t.b; R.vc[s] = (signed char)t.c;
    for (int g = 0; g < 4; ++g) {
        bool dup = false;
        for (int h = 0; h < g; ++h)
            if (t3_eq(im[h], im[g])) dup = true;
        R.p[g][s] = dup ? (short)-1 : (short)rank_of(im[g]);
    }
    ++s;
}

constexpr RepTables make_tables() {
    RepTables R{};
    int s = 0;
    consider(R, s, T3{18, 18, 18});
    for (int a = 0; a < NVARS; ++a) consider(R, s, T3{a, 18, 18});
    for (int a = 0; a < NVARS; ++a)
        for (int b = a; b < NVARS; ++b) consider(R, s, T3{a, b, 18});
    for (int a = 0; a < NVARS; ++a)
        for (int b = a; b < NVARS; ++b)
            for (int c = b; c < NVARS; ++c) consider(R, s, T3{a, b, c});
    R.count = s;
    for (; s < NSLOTS; ++s) {
        R.va[s] = 19; R.vb[s] = 19; R.vc[s] = 19;
        for (int g = 0; g < 4; ++g) R.p[g][s] = -1;
    }
    return R;
}

constexpr RepTables h_tab = make_tables();          // compile-time use
static_assert(h_tab.count == 342, "orbit enumeration must give 342 rep slots");
__device__ const RepTables d_tab = make_tables();   // runtime use (prep)

// Module-scope staging buffer for the prepped W table (NOT harness workspace).
__device__ __align__(16) short g_wf[WF_SHORTS];

// ---- bf16 pair pack --------------------------------------------------------

#if __has_builtin(__builtin_amdgcn_cvt_pk_bf16_f32)
typedef __bf16 bf16x2 __attribute__((ext_vector_type(2)));
__device__ __forceinline__ unsigned pack2(float f0, float f1) {
    bf16x2 r = __builtin_amdgcn_cvt_pk_bf16_f32(f0, f1);   // lo=f0, hi=f1, RNE
    return __builtin_bit_cast(unsigned, r);
}
#else
__device__ __forceinline__ unsigned pack2(float f0, float f1) {
    unsigned u0 = __float_as_uint(f0) + 0x8000u;
    unsigned u1 = __float_as_uint(f1) + 0x8000u;
    return __builtin_amdgcn_perm(u1, u0, 0x07060302u);     // lo=bf16(f0), hi=bf16(f1)
}
#endif

// ---- main kernel -----------------------------------------------------------

template <int S>
__device__ __forceinline__ float term_val(const float (&x)[NVARS]) {
    constexpr int a = h_tab.va[S], b = h_tab.vb[S], c = h_tab.vc[S];
    if constexpr (a >= 19)      return 0.0f;                 // pad slot
    else if constexpr (a == 18) return 1.0f;                 // constant
    else if constexpr (b == 18) return x[a];
    else if constexpr (c == 18) return x[a] * x[b];
    else                        return x[a] * x[b] * x[c];
}

union AFrag { unsigned u[4]; short8 v; };

template <int CI, int... I>
__device__ __forceinline__ void eval8(const float (&x)[NVARS], float (&t)[8],
                                      std::integer_sequence<int, I...>) {
    ((t[I] = term_val<CI * 8 + I>(x)), ...);
}

template <int CI>
__device__ __forceinline__ void kstep(const float (&xA)[NVARS], const float (&xB)[NVARS],
                                      const short* p0, const short* p1,
                                      f32x4& acc00, f32x4& acc01,
                                      f32x4& acc10, f32x4& acc11) {
    float tA[8], tB[8];
    eval8<CI>(xA, tA, std::make_integer_sequence<int, 8>{});
    eval8<CI>(xB, tB, std::make_integer_sequence<int, 8>{});
    AFrag afA, afB;
#pragma unroll
    for (int j = 0; j < 4; ++j) {
        afA.u[j] = pack2(tA[2 * j], tA[2 * j + 1]);
        afB.u[j] = pack2(tB[2 * j], tB[2 * j + 1]);
    }
    short8 b0 = *(const short8*)(p0 + CI * 512);   // tile0 frag, ds_read_b128
    short8 b1 = *(const short8*)(p1 + CI * 72);    // compact tile1 frag (zero slot for n>=2)
    acc00 = __builtin_amdgcn_mfma_f32_16x16x32_bf16(afA.v, b0, acc00, 0, 0, 0);
    acc10 = __builtin_amdgcn_mfma_f32_16x16x32_bf16(afB.v, b0, acc10, 0, 0, 0);
    acc01 = __builtin_amdgcn_mfma_f32_16x16x32_bf16(afA.v, b1, acc01, 0, 0, 0);
    acc11 = __builtin_amdgcn_mfma_f32_16x16x32_bf16(afB.v, b1, acc11, 0, 0, 0);
}

template <int... CI>
__device__ __forceinline__ void kloop(const float (&xA)[NVARS], const float (&xB)[NVARS],
                                      const short* p0, const short* p1,
                                      f32x4& acc00, f32x4& acc01,
                                      f32x4& acc10, f32x4& acc11,
                                      std::integer_sequence<int, CI...>) {
    (kstep<CI>(xA, xB, p0, p1, acc00, acc01, acc10, acc11), ...);
}

__device__ __forceinline__ void load_x(const float* __restrict__ z,
                                       const float* __restrict__ betas,
                                       int arow, bool s1, bool s2, float (&x)[NVARS]) {
    float x0[NVARS];
    const float4* z4 = (const float4*)(z + (size_t)arow * 16);
    float4 v0 = z4[0], v1 = z4[1], v2 = z4[2], v3 = z4[3];
    x0[0]  = v0.x; x0[1]  = v0.y; x0[2]  = v0.z; x0[3]  = v0.w;
    x0[4]  = v1.x; x0[5]  = v1.y; x0[6]  = v1.z; x0[7]  = v1.w;
    x0[8]  = v2.x; x0[9]  = v2.y; x0[10] = v2.z; x0[11] = v2.w;
    x0[12] = v3.x; x0[13] = v3.y; x0[14] = v3.z; x0[15] = v3.w;
    const float2 b2 = *(const float2*)(betas + (size_t)arow * 2);
    x0[16] = b2.x; x0[17] = b2.y;
    float y[NVARS];
#pragma unroll
    for (int v = 0; v < NVARS; ++v) y[v] = s1 ? x0[rho1(v)] : x0[v];
#pragma unroll
    for (int v = 0; v < NVARS; ++v) x[v] = s2 ? y[rho2v(v)] : y[v];
}

__global__ __launch_bounds__(1024, 4) void vindy_mfma(const float* __restrict__ z,
                                                      const float* __restrict__ betas,
                                                      float* __restrict__ out) {
    // 82944 B: only 1 block/CU can fit -> occupancy target is unambiguously
    // 4 waves/EU -> allocator budget 128 VGPRs (round-0's proven regime).
    __shared__ __align__(16) short ldsW[LDS_SHORTS];

    // stage all W fragments once per block (flat 16B copies, fully coalesced)
    {
        const float4* src = (const float4*)g_wf;
        float4* dst = (float4*)ldsW;
        for (int i = threadIdx.x; i < WF_SHORTS / 8; i += 1024) dst[i] = src[i];
    }
    __syncthreads();

    const int lane = threadIdx.x & 63;
    const int wave = threadIdx.x >> 6;   // 0..15
    const int g    = lane >> 4;          // rho-power / k-quad
    const int n    = lane & 15;          // A-row within tile; C col
    const int rowbase = blockIdx.x * 512 + wave * 32;

    const bool s1 = (g & 1) != 0;
    const bool s2 = (g & 2) != 0;
    float xA[NVARS], xB[NVARS];
    load_x(z, betas, rowbase + n,      s1, s2, xA);
    load_x(z, betas, rowbase + 16 + n, s1, s2, xB);

    const short* p0 = ldsW + lane * 8;                                    // tile0 base
    const short* p1 = ldsW + WF0_SHORTS + (n < 2 ? (g * 2 + n) * 8 : 64); // tile1 / zero slot

    f32x4 acc00, acc01, acc10, acc11;
#pragma unroll
    for (int i = 0; i < 4; ++i) { acc00[i] = 0.0f; acc01[i] = 0.0f; acc10[i] = 0.0f; acc11[i] = 0.0f; }

    kloop(xA, xB, p0, p1, acc00, acc01, acc10, acc11,
          std::make_integer_sequence<int, NCHUNKS>{});

    // C/D 16x16 layout: col = lane&15, row = g*4 + reg
    float* o0 = out + (size_t)(rowbase + g * 4) * NOUT;
    float* o1 = out + (size_t)(rowbase + 16 + g * 4) * NOUT;
#pragma unroll
    for (int r = 0; r < 4; ++r) {
        o0[(size_t)r * NOUT + n] = acc00[r];
        o1[(size_t)r * NOUT + n] = acc10[r];
    }
    if (n < 2) {
#pragma unroll
        for (int r = 0; r < 4; ++r) {
            o0[(size_t)r * NOUT + 16 + n] = acc01[r];
            o1[(size_t)r * NOUT + 16 + n] = acc11[r];
        }
    }
}

// ---- prep: W fragments in staged layout ------------------------------------
// region 0 (tile0, cols 0-15): wf[c*512 + l*8 + j] = W[p[l>>4][c*8+j]][l&15]
// region 1 (tile1 compact, 72 shorts/chunk):
//   q = 0..7:  wf[WF0 + c*72 + q*8 + j] = W[p[q>>1][c*8+j]][16+(q&1)]
//   q = 8:     zero slot (read by lanes n>=2)

__global__ void prep_wfrag(const float* __restrict__ xi, const float* __restrict__ mask) {
    int i = blockIdx.x * blockDim.x + threadIdx.x;
    if (i >= WF_SHORTS) return;
    float v = 0.0f;
    if (i < WF0_SHORTS) {
        int j = i & 7, l = (i >> 3) & 63, c = i >> 9;
        int col = l & 15;
        int p = d_tab.p[l >> 4][c * 8 + j];
        if (p >= 0) v = xi[p * NOUT + col] * mask[p * NOUT + col];
    } else {
        int i2 = i - WF0_SHORTS;
        int c = i2 / 72;
        int r = i2 - c * 72;
        int q = r >> 3, j = r & 7;
        if (q < 8) {
            int col = 16 + (q & 1);
            int p = d_tab.p[q >> 1][c * 8 + j];
            if (p >= 0) v = xi[p * NOUT + col] * mask[p * NOUT + col];
        }
    }
    g_wf[i] = __builtin_bit_cast(short, __float2bfloat16(v));
}

extern "C" void kernel_launch(void* const* d_in, const int* in_sizes, int n_in,
                              void* d_out, int out_size, void* d_ws, size_t ws_size,
                              hipStream_t stream) {
    const float* z     = (const float*)d_in[0];
    const float* betas = (const float*)d_in[1];
    const float* xi    = (const float*)d_in[2];
    const float* mask  = (const float*)d_in[3];
    float* out = (float*)d_out;
    (void)d_ws; (void)ws_size;   // workspace unused (poison fill is unconditional anyway)

    prep_wfrag<<<(WF_SHORTS + 255) / 256, 256, 0, stream>>>(xi, mask);
    vindy_mfma<<<NROWS / 512, 1024, 0, stream>>>(z, betas, out);
}

// Round 6
// 89.372 us; speedup vs baseline: 2.0541x; 1.1650x over previous
//
#include <hip/hip_runtime.h>
#include <hip/hip_bf16.h>
#include <utility>

// out[131072,18] = theta(x)[131072,1330] @ (xi*mask)[1330,18]
// bf16 MFMA GEMM via mfma_f32_16x16x32_bf16.
// Order-4 symmetry rho = (0123)(4567)(89AB)(CDEF)(16 17): 1330 monomials ->
// 342 rep slots -> 43 K-chunks of 32. Lane-quad g evaluates the same
// compile-time rep expressions on rho^g-permuted inputs.
// Round-12 structure: DESIGN TO 64 ARCH VGPRS (the empirical wall).
//  Rounds 2/3/5 proved: at >=512-thread blocks the allocator caps arch
//  VGPRs at 64 regardless of launch_bounds 2nd arg / waves_per_eu / LDS
//  pinning (likely the MFMA arch/accum file split), and the 2-tile-per-wave
//  body (~100 live regs) then spills 40-60 MB to scratch. R4's no-hint
//  variant (128 regs) thrashed scratch through its runtime loop.
//  Fix: SINGLE 16-row tile per wave. Live set: x[18] + af[4] + b frags [8]
//  + transients ~10 = ~45 arch VGPRs + 8 AGPR accum -> zero spills AT the
//  64-reg target. Extra cost: b0 ds_read per row doubles (b1 is
//  quad-broadcast, cheap) -> ~7-10 us LDS pipe, overlapped at 6 waves/EU.
//  - 512-thr blocks (8 waves x 16 rows = 128 rows), grid = 1024;
//    LDS 50224 B -> 3 blocks/CU, 24 waves/CU.
//  - W table in module-scope g_wf (prep dispatch + linear float4 staging).
//    The harness's 256 MiB workspace poison fill is UNCONDITIONAL (~45 us
//    floor) + ~13 us aux/gaps; vindy itself is the only lever.

constexpr int NVARS   = 18;
constexpr int NOUT    = 18;
constexpr int NROWS   = 131072;
constexpr int NCHUNKS = 43;             // K = 43*32 = 1376
constexpr int NSLOTS  = NCHUNKS * 8;    // 344 (342 used + 2 pad)

constexpr int WF0_SHORTS = NCHUNKS * 512;   // tile0 frags: 22016 shorts (44032 B)
constexpr int WF1_SHORTS = NCHUNKS * 72;    // compact tile1 + zero slot: 3096 shorts
constexpr int WF_SHORTS  = WF0_SHORTS + WF1_SHORTS;  // 25112 shorts = 50224 B

typedef __attribute__((ext_vector_type(8))) short short8;
typedef __attribute__((ext_vector_type(4))) float f32x4;

struct T3 { int a, b, c; };   // sorted ascending; 18 = unused factor; 19 = pad

constexpr int rho1(int v) {
    if (v < 16)  return (v & ~3) | ((v + 1) & 3);
    if (v == 16) return 17;
    if (v == 17) return 16;
    return v;
}
constexpr int rho2v(int v) { return rho1(rho1(v)); }

constexpr T3 sort3(int u0, int u1, int u2) {
    int t = 0;
    if (u0 > u1) { t = u0; u0 = u1; u1 = t; }
    if (u1 > u2) { t = u1; u1 = u2; u2 = t; }
    if (u0 > u1) { t = u0; u0 = u1; u1 = t; }
    return T3{u0, u1, u2};
}
constexpr T3 rho3(T3 t) { return sort3(rho1(t.a), rho1(t.b), rho1(t.c)); }

constexpr bool t3_less(T3 x, T3 y) {
    if (x.a != y.a) return x.a < y.a;
    if (x.b != y.b) return x.b < y.b;
    return x.c < y.c;
}
constexpr bool t3_eq(T3 x, T3 y) { return x.a == y.a && x.b == y.b && x.c == y.c; }

constexpr int rank_of(T3 t) {
    int deg = (t.a < 18) + (t.b < 18) + (t.c < 18);
    if (deg == 0) return 0;
    if (deg == 1) return 1 + t.a;
    if (deg == 2) {
        int r = 19;
        for (int a = 0; a < t.a; ++a) r += 18 - a;
        return r + (t.b - t.a);
    }
    int r = 190;
    for (int a = 0; a < t.a; ++a) { int n = 18 - a; r += n * (n + 1) / 2; }
    for (int b = t.a; b < t.b; ++b) r += 18 - b;
    return r + (t.c - t.b);
}

struct RepTables {
    signed char va[NSLOTS], vb[NSLOTS], vc[NSLOTS];
    short p[4][NSLOTS];   // flat term index for group g's k-position; -1 => zero W
    int count;
};

constexpr void consider(RepTables& R, int& s, T3 t) {
    T3 im[4] = {t, T3{0, 0, 0}, T3{0, 0, 0}, T3{0, 0, 0}};
    im[1] = rho3(im[0]);
    im[2] = rho3(im[1]);
    im[3] = rho3(im[2]);
    for (int g = 1; g < 4; ++g)
        if (t3_less(im[g], t)) return;   // not the orbit representative
    R.va[s] = (signed char)t.a; R.vb[s] = (signed char)t.b; R.vc[s] = (signed char)t.c;
    for (int g = 0; g < 4; ++g) {
        bool dup = false;
        for (int h = 0; h < g; ++h)
            if (t3_eq(im[h], im[g])) dup = true;
        R.p[g][s] = dup ? (short)-1 : (short)rank_of(im[g]);
    }
    ++s;
}

constexpr RepTables make_tables() {
    RepTables R{};
    int s = 0;
    consider(R, s, T3{18, 18, 18});
    for (int a = 0; a < NVARS; ++a) consider(R, s, T3{a, 18, 18});
    for (int a = 0; a < NVARS; ++a)
        for (int b = a; b < NVARS; ++b) consider(R, s, T3{a, b, 18});
    for (int a = 0; a < NVARS; ++a)
        for (int b = a; b < NVARS; ++b)
            for (int c = b; c < NVARS; ++c) consider(R, s, T3{a, b, c});
    R.count = s;
    for (; s < NSLOTS; ++s) {
        R.va[s] = 19; R.vb[s] = 19; R.vc[s] = 19;
        for (int g = 0; g < 4; ++g) R.p[g][s] = -1;
    }
    return R;
}

constexpr RepTables h_tab = make_tables();          // compile-time use
static_assert(h_tab.count == 342, "orbit enumeration must give 342 rep slots");
__device__ const RepTables d_tab = make_tables();   // runtime use (prep)

// Module-scope staging buffer for the prepped W table (NOT harness workspace).
__device__ __align__(16) short g_wf[WF_SHORTS];

// ---- bf16 pair pack --------------------------------------------------------

#if __has_builtin(__builtin_amdgcn_cvt_pk_bf16_f32)
typedef __bf16 bf16x2 __attribute__((ext_vector_type(2)));
__device__ __forceinline__ unsigned pack2(float f0, float f1) {
    bf16x2 r = __builtin_amdgcn_cvt_pk_bf16_f32(f0, f1);   // lo=f0, hi=f1, RNE
    return __builtin_bit_cast(unsigned, r);
}
#else
__device__ __forceinline__ unsigned pack2(float f0, float f1) {
    unsigned u0 = __float_as_uint(f0) + 0x8000u;
    unsigned u1 = __float_as_uint(f1) + 0x8000u;
    return __builtin_amdgcn_perm(u1, u0, 0x07060302u);     // lo=bf16(f0), hi=bf16(f1)
}
#endif

// ---- main kernel -----------------------------------------------------------

template <int S>
__device__ __forceinline__ float term_val(const float (&x)[NVARS]) {
    constexpr int a = h_tab.va[S], b = h_tab.vb[S], c = h_tab.vc[S];
    if constexpr (a >= 19)      return 0.0f;                 // pad slot
    else if constexpr (a == 18) return 1.0f;                 // constant
    else if constexpr (b == 18) return x[a];
    else if constexpr (c == 18) return x[a] * x[b];
    else                        return x[a] * x[b] * x[c];
}

union AFrag { unsigned u[4]; short8 v; };

template <int CI, int... I>
__device__ __forceinline__ void eval8(const float (&x)[NVARS], float (&t)[8],
                                      std::integer_sequence<int, I...>) {
    ((t[I] = term_val<CI * 8 + I>(x)), ...);
}

template <int CI>
__device__ __forceinline__ void kstep(const float (&x)[NVARS],
                                      const short* p0, const short* p1,
                                      f32x4& acc0, f32x4& acc1) {
    float t[8];
    eval8<CI>(x, t, std::make_integer_sequence<int, 8>{});
    AFrag af;
#pragma unroll
    for (int j = 0; j < 4; ++j) af.u[j] = pack2(t[2 * j], t[2 * j + 1]);
    short8 b0 = *(const short8*)(p0 + CI * 512);   // tile0 frag, ds_read_b128
    short8 b1 = *(const short8*)(p1 + CI * 72);    // compact tile1 frag (zero slot for n>=2)
    acc0 = __builtin_amdgcn_mfma_f32_16x16x32_bf16(af.v, b0, acc0, 0, 0, 0);
    acc1 = __builtin_amdgcn_mfma_f32_16x16x32_bf16(af.v, b1, acc1, 0, 0, 0);
}

template <int... CI>
__device__ __forceinline__ void kloop(const float (&x)[NVARS],
                                      const short* p0, const short* p1,
                                      f32x4& acc0, f32x4& acc1,
                                      std::integer_sequence<int, CI...>) {
    (kstep<CI>(x, p0, p1, acc0, acc1), ...);
}

__device__ __forceinline__ void load_x(const float* __restrict__ z,
                                       const float* __restrict__ betas,
                                       int arow, bool s1, bool s2, float (&x)[NVARS]) {
    float x0[NVARS];
    const float4* z4 = (const float4*)(z + (size_t)arow * 16);
    float4 v0 = z4[0], v1 = z4[1], v2 = z4[2], v3 = z4[3];
    x0[0]  = v0.x; x0[1]  = v0.y; x0[2]  = v0.z; x0[3]  = v0.w;
    x0[4]  = v1.x; x0[5]  = v1.y; x0[6]  = v1.z; x0[7]  = v1.w;
    x0[8]  = v2.x; x0[9]  = v2.y; x0[10] = v2.z; x0[11] = v2.w;
    x0[12] = v3.x; x0[13] = v3.y; x0[14] = v3.z; x0[15] = v3.w;
    const float2 b2 = *(const float2*)(betas + (size_t)arow * 2);
    x0[16] = b2.x; x0[17] = b2.y;
    float y[NVARS];
#pragma unroll
    for (int v = 0; v < NVARS; ++v) y[v] = s1 ? x0[rho1(v)] : x0[v];
#pragma unroll
    for (int v = 0; v < NVARS; ++v) x[v] = s2 ? y[rho2v(v)] : y[v];
}

__global__ __launch_bounds__(512, 4) void vindy_mfma(const float* __restrict__ z,
                                                     const float* __restrict__ betas,
                                                     float* __restrict__ out) {
    __shared__ __align__(16) short ldsW[WF_SHORTS];   // 50224 B -> 3 blocks/CU

    // stage all W fragments once per block (flat 16B copies, fully coalesced)
    {
        const float4* src = (const float4*)g_wf;
        float4* dst = (float4*)ldsW;
        for (int i = threadIdx.x; i < WF_SHORTS / 8; i += 512) dst[i] = src[i];
    }
    __syncthreads();

    const int lane = threadIdx.x & 63;
    const int wave = threadIdx.x >> 6;   // 0..7
    const int g    = lane >> 4;          // rho-power / k-quad
    const int n    = lane & 15;          // A-row within tile; C col
    const int row0 = blockIdx.x * 128 + wave * 16;   // ONE 16-row tile per wave

    const bool s1 = (g & 1) != 0;
    const bool s2 = (g & 2) != 0;
    float x[NVARS];
    load_x(z, betas, row0 + n, s1, s2, x);

    const short* p0 = ldsW + lane * 8;                                    // tile0 base
    const short* p1 = ldsW + WF0_SHORTS + (n < 2 ? (g * 2 + n) * 8 : 64); // tile1 / zero slot

    f32x4 acc0, acc1;
#pragma unroll
    for (int i = 0; i < 4; ++i) { acc0[i] = 0.0f; acc1[i] = 0.0f; }

    kloop(x, p0, p1, acc0, acc1, std::make_integer_sequence<int, NCHUNKS>{});

    // C/D 16x16 layout: col = lane&15, row = g*4 + reg
    float* o = out + (size_t)(row0 + g * 4) * NOUT;
#pragma unroll
    for (int r = 0; r < 4; ++r) o[(size_t)r * NOUT + n] = acc0[r];
    if (n < 2) {
#pragma unroll
        for (int r = 0; r < 4; ++r) o[(size_t)r * NOUT + 16 + n] = acc1[r];
    }
}

// ---- prep: W fragments in staged layout ------------------------------------
// region 0 (tile0, cols 0-15): wf[c*512 + l*8 + j] = W[p[l>>4][c*8+j]][l&15]
// region 1 (tile1 compact, 72 shorts/chunk):
//   q = 0..7:  wf[WF0 + c*72 + q*8 + j] = W[p[q>>1][c*8+j]][16+(q&1)]
//   q = 8:     zero slot (read by lanes n>=2)

__global__ void prep_wfrag(const float* __restrict__ xi, const float* __restrict__ mask) {
    int i = blockIdx.x * blockDim.x + threadIdx.x;
    if (i >= WF_SHORTS) return;
    float v = 0.0f;
    if (i < WF0_SHORTS) {
        int j = i & 7, l = (i >> 3) & 63, c = i >> 9;
        int col = l & 15;
        int p = d_tab.p[l >> 4][c * 8 + j];
        if (p >= 0) v = xi[p * NOUT + col] * mask[p * NOUT + col];
    } else {
        int i2 = i - WF0_SHORTS;
        int c = i2 / 72;
        int r = i2 - c * 72;
        int q = r >> 3, j = r & 7;
        if (q < 8) {
            int col = 16 + (q & 1);
            int p = d_tab.p[q >> 1][c * 8 + j];
            if (p >= 0) v = xi[p * NOUT + col] * mask[p * NOUT + col];
        }
    }
    g_wf[i] = __builtin_bit_cast(short, __float2bfloat16(v));
}

extern "C" void kernel_launch(void* const* d_in, const int* in_sizes, int n_in,
                              void* d_out, int out_size, void* d_ws, size_t ws_size,
                              hipStream_t stream) {
    const float* z     = (const float*)d_in[0];
    const float* betas = (const float*)d_in[1];
    const float* xi    = (const float*)d_in[2];
    const float* mask  = (const float*)d_in[3];
    float* out = (float*)d_out;
    (void)d_ws; (void)ws_size;   // workspace unused (poison fill is unconditional anyway)

    prep_wfrag<<<(WF_SHORTS + 255) / 256, 256, 0, stream>>>(xi, mask);
    vindy_mfma<<<NROWS / 128, 512, 0, stream>>>(z, betas, out);
}

// Round 7
// 86.041 us; speedup vs baseline: 2.1337x; 1.0387x over previous
//
#include <hip/hip_runtime.h>
#include <hip/hip_bf16.h>
#include <utility>

// out[131072,18] = theta(x)[131072,1330] @ (xi*mask)[1330,18]
// bf16 MFMA GEMM, round 13: switch to mfma_f32_32x32x16_bf16.
// Order-4 symmetry rho = (0123)(4567)(89AB)(CDEF)(16 17): 1330 monomials ->
// 342 rep slots. 32x32 A-layout has 2 K-halves per wave (h = lane>>5,
// k = h*8+j), so one wave covers 32 ROWS and the 4 rho-powers are covered by
// two 43-chunk phases: chunks 0..42 use g in {0,1} (= h), chunks 43..85 use
// g in {2,3} (= h+2). The phase switch is x2[v] = x1[rho2(v)] - a pure
// compile-time register renaming, free.
// Per-row vs round 6 (16x16): ds_reads HALVE (86/32rows vs 86/16rows), MFMA
// cycles 26.9 -> 21.5/row, term evals unchanged, live set still ~56 regs
// (the empirical 64-VGPR wall from rounds 2/3/5 is respected by design).
// Geometry: 512-thr blocks (8 waves x 32 rows = 256 rows), grid = 512 =
// EXACTLY 2 blocks/CU (LDS padded to 64 KiB makes >2 impossible -> uniform
// distribution), zero tail, 4 waves/SIMD.
// B-table in LDS: per chunk [h][19 cols][8 shorts] (608 B stride); col 18 is
// a zero slot for lanes col>=18 (broadcast read = free). Total 52288 B.
// Harness floor: unconditional 256 MiB workspace poison fill (~42 us) +
// prep/gaps ~16 us; vindy is the only lever.

constexpr int NVARS   = 18;
constexpr int NOUT    = 18;
constexpr int NROWS   = 131072;
constexpr int NCHUNKS = 43;             // flat K = 43*32 = 1376 (4 g x 8 slots)
constexpr int NSLOTS  = NCHUNKS * 8;    // 344 (342 used + 2 pad)

constexpr int CH_STRIDE = 304;                    // shorts per chunk: 2h x 19col x 8j
constexpr int WF2_SHORTS = 86 * CH_STRIDE;        // 26144 shorts = 52288 B
constexpr int LDS_SHORTS = 32768;                 // 65536 B -> hard cap 2 blocks/CU

typedef __attribute__((ext_vector_type(8)))  short short8;
typedef __attribute__((ext_vector_type(16))) float f32x16;

struct T3 { int a, b, c; };   // sorted ascending; 18 = unused factor; 19 = pad

constexpr int rho1(int v) {
    if (v < 16)  return (v & ~3) | ((v + 1) & 3);
    if (v == 16) return 17;
    if (v == 17) return 16;
    return v;
}
constexpr int rho2v(int v) { return rho1(rho1(v)); }

constexpr T3 sort3(int u0, int u1, int u2) {
    int t = 0;
    if (u0 > u1) { t = u0; u0 = u1; u1 = t; }
    if (u1 > u2) { t = u1; u1 = u2; u2 = t; }
    if (u0 > u1) { t = u0; u0 = u1; u1 = t; }
    return T3{u0, u1, u2};
}
constexpr T3 rho3(T3 t) { return sort3(rho1(t.a), rho1(t.b), rho1(t.c)); }

constexpr bool t3_less(T3 x, T3 y) {
    if (x.a != y.a) return x.a < y.a;
    if (x.b != y.b) return x.b < y.b;
    return x.c < y.c;
}
constexpr bool t3_eq(T3 x, T3 y) { return x.a == y.a && x.b == y.b && x.c == y.c; }

constexpr int rank_of(T3 t) {
    int deg = (t.a < 18) + (t.b < 18) + (t.c < 18);
    if (deg == 0) return 0;
    if (deg == 1) return 1 + t.a;
    if (deg == 2) {
        int r = 19;
        for (int a = 0; a < t.a; ++a) r += 18 - a;
        return r + (t.b - t.a);
    }
    int r = 190;
    for (int a = 0; a < t.a; ++a) { int n = 18 - a; r += n * (n + 1) / 2; }
    for (int b = t.a; b < t.b; ++b) r += 18 - b;
    return r + (t.c - t.b);
}

struct RepTables {
    signed char va[NSLOTS], vb[NSLOTS], vc[NSLOTS];
    short p[4][NSLOTS];   // flat term index for group g's k-position; -1 => zero W
    int count;
};

constexpr void consider(RepTables& R, int& s, T3 t) {
    T3 im[4] = {t, T3{0, 0, 0}, T3{0, 0, 0}, T3{0, 0, 0}};
    im[1] = rho3(im[0]);
    im[2] = rho3(im[1]);
    im[3] = rho3(im[2]);
    for (int g = 1; g < 4; ++g)
        if (t3_less(im[g], t)) return;   // not the orbit representative
    R.va[s] = (signed char)t.a; R.vb[s] = (signed char)t.b; R.vc[s] = (signed char)t.c;
    for (int g = 0; g < 4; ++g) {
        bool dup = false;
        for (int h = 0; h < g; ++h)
            if (t3_eq(im[h], im[g])) dup = true;
        R.p[g][s] = dup ? (short)-1 : (short)rank_of(im[g]);
    }
    ++s;
}

constexpr RepTables make_tables() {
    RepTables R{};
    int s = 0;
    consider(R, s, T3{18, 18, 18});
    for (int a = 0; a < NVARS; ++a) consider(R, s, T3{a, 18, 18});
    for (int a = 0; a < NVARS; ++a)
        for (int b = a; b < NVARS; ++b) consider(R, s, T3{a, b, 18});
    for (int a = 0; a < NVARS; ++a)
        for (int b = a; b < NVARS; ++b)
            for (int c = b; c < NVARS; ++c) consider(R, s, T3{a, b, c});
    R.count = s;
    for (; s < NSLOTS; ++s) {
        R.va[s] = 19; R.vb[s] = 19; R.vc[s] = 19;
        for (int g = 0; g < 4; ++g) R.p[g][s] = -1;
    }
    return R;
}

constexpr RepTables h_tab = make_tables();          // compile-time use
static_assert(h_tab.count == 342, "orbit enumeration must give 342 rep slots");
__device__ const RepTables d_tab = make_tables();   // runtime use (prep)

// Module-scope staging buffer for the prepped W table (NOT harness workspace).
__device__ __align__(16) short g_wf2[WF2_SHORTS];

// ---- bf16 pair pack --------------------------------------------------------

#if __has_builtin(__builtin_amdgcn_cvt_pk_bf16_f32)
typedef __bf16 bf16x2 __attribute__((ext_vector_type(2)));
__device__ __forceinline__ unsigned pack2(float f0, float f1) {
    bf16x2 r = __builtin_amdgcn_cvt_pk_bf16_f32(f0, f1);   // lo=f0, hi=f1, RNE
    return __builtin_bit_cast(unsigned, r);
}
#else
__device__ __forceinline__ unsigned pack2(float f0, float f1) {
    unsigned u0 = __float_as_uint(f0) + 0x8000u;
    unsigned u1 = __float_as_uint(f1) + 0x8000u;
    return __builtin_amdgcn_perm(u1, u0, 0x07060302u);     // lo=bf16(f0), hi=bf16(f1)
}
#endif

// ---- main kernel -----------------------------------------------------------

template <int S>
__device__ __forceinline__ float term_val(const float (&x)[NVARS]) {
    constexpr int a = h_tab.va[S], b = h_tab.vb[S], c = h_tab.vc[S];
    if constexpr (a >= 19)      return 0.0f;                 // pad slot
    else if constexpr (a == 18) return 1.0f;                 // constant
    else if constexpr (b == 18) return x[a];
    else if constexpr (c == 18) return x[a] * x[b];
    else                        return x[a] * x[b] * x[c];
}

union AFrag { unsigned u[4]; short8 v; };

// Fused eval+pack: keeps only 2 term floats live at a time.
template <int S, int... J>
__device__ __forceinline__ void pack8(const float (&x)[NVARS], AFrag& af,
                                      std::integer_sequence<int, J...>) {
    ((af.u[J] = pack2(term_val<S + 2 * J>(x), term_val<S + 2 * J + 1>(x))), ...);
}

template <int CI>
__device__ __forceinline__ void kstep32(const float (&x)[NVARS],
                                        const short* pB, f32x16& acc) {
    constexpr int S = (CI < 43 ? CI : CI - 43) * 8;   // slot base for this chunk
    AFrag af;
    pack8<S>(x, af, std::make_integer_sequence<int, 4>{});
    short8 b = *(const short8*)(pB + CI * CH_STRIDE);   // ds_read_b128
    acc = __builtin_amdgcn_mfma_f32_32x32x16_bf16(af.v, b, acc, 0, 0, 0);
}

template <int BASE, int... CI>
__device__ __forceinline__ void kloop32(const float (&x)[NVARS],
                                        const short* pB, f32x16& acc,
                                        std::integer_sequence<int, CI...>) {
    (kstep32<BASE + CI>(x, pB, acc), ...);
}

__device__ __forceinline__ void load_x(const float* __restrict__ z,
                                       const float* __restrict__ betas,
                                       int arow, bool s1, float (&x)[NVARS]) {
    float x0[NVARS];
    const float4* z4 = (const float4*)(z + (size_t)arow * 16);
    float4 v0 = z4[0], v1 = z4[1], v2 = z4[2], v3 = z4[3];
    x0[0]  = v0.x; x0[1]  = v0.y; x0[2]  = v0.z; x0[3]  = v0.w;
    x0[4]  = v1.x; x0[5]  = v1.y; x0[6]  = v1.z; x0[7]  = v1.w;
    x0[8]  = v2.x; x0[9]  = v2.y; x0[10] = v2.z; x0[11] = v2.w;
    x0[12] = v3.x; x0[13] = v3.y; x0[14] = v3.z; x0[15] = v3.w;
    const float2 b2 = *(const float2*)(betas + (size_t)arow * 2);
    x0[16] = b2.x; x0[17] = b2.y;
#pragma unroll
    for (int v = 0; v < NVARS; ++v) x[v] = s1 ? x0[rho1(v)] : x0[v];
}

__global__ __launch_bounds__(512, 4) void vindy_mfma(const float* __restrict__ z,
                                                     const float* __restrict__ betas,
                                                     float* __restrict__ out) {
    __shared__ __align__(16) short ldsW[LDS_SHORTS];   // 64 KiB -> hard 2 blocks/CU

    // stage all W fragments once per block (flat 16B copies, fully coalesced)
    {
        const float4* src = (const float4*)g_wf2;
        float4* dst = (float4*)ldsW;
        for (int i = threadIdx.x; i < WF2_SHORTS / 8; i += 512) dst[i] = src[i];
    }
    __syncthreads();

    const int lane = threadIdx.x & 63;
    const int wave = threadIdx.x >> 6;   // 0..7
    const int h    = lane >> 5;          // K-half -> rho-power h (phase 1), h+2 (phase 2)
    const int col  = lane & 31;          // A row within tile; C col
    const int row0 = blockIdx.x * 256 + wave * 32;

    // x permuted by rho^h for phase 1
    float x1[NVARS];
    load_x(z, betas, row0 + col, h != 0, x1);

    const int col_eff = (col < NOUT) ? col : NOUT;   // col 18 = zero slot
    const short* pB = ldsW + h * 152 + col_eff * 8;

    f32x16 acc;
#pragma unroll
    for (int i = 0; i < 16; ++i) acc[i] = 0.0f;

    // phase 1: chunks 0..42, g = h
    kloop32<0>(x1, pB, acc, std::make_integer_sequence<int, 43>{});

    // phase switch: rho^2 renaming (compile-time register permutation, free)
    float x2[NVARS];
#pragma unroll
    for (int v = 0; v < NVARS; ++v) x2[v] = x1[rho2v(v)];

    // phase 2: chunks 43..85, g = h + 2
    kloop32<43>(x2, pB, acc, std::make_integer_sequence<int, 43>{});

    // C/D 32x32 layout: col = lane&31, row = (reg&3) + 8*(reg>>2) + 4*h
    if (col < NOUT) {
#pragma unroll
        for (int q = 0; q < 4; ++q) {
#pragma unroll
            for (int r = 0; r < 4; ++r) {
                int row = r + 8 * q + 4 * h;
                out[(size_t)(row0 + row) * NOUT + col] = acc[q * 4 + r];
            }
        }
    }
}

// ---- prep: W fragments in staged layout ------------------------------------
// g_wf2[c*304 + h*152 + col*8 + j]:
//   col < 18:  W[p[g][s]][col],  g = (c<43 ? h : 2+h),  s = (c<43 ? c : c-43)*8+j
//   col == 18: zero slot (read broadcast by lanes col>=18)

__global__ void prep_wfrag(const float* __restrict__ xi, const float* __restrict__ mask) {
    int i = blockIdx.x * blockDim.x + threadIdx.x;
    if (i >= WF2_SHORTS) return;
    int c  = i / CH_STRIDE;
    int r  = i - c * CH_STRIDE;
    int h  = r / 152;
    int r2 = r - h * 152;
    int col = r2 >> 3, j = r2 & 7;
    float v = 0.0f;
    if (col < NOUT) {
        int g = (c < 43 ? 0 : 2) + h;
        int s = (c < 43 ? c : c - 43) * 8 + j;
        int p = d_tab.p[g][s];
        if (p >= 0) v = xi[p * NOUT + col] * mask[p * NOUT + col];
    }
    g_wf2[i] = __builtin_bit_cast(short, __float2bfloat16(v));
}

extern "C" void kernel_launch(void* const* d_in, const int* in_sizes, int n_in,
                              void* d_out, int out_size, void* d_ws, size_t ws_size,
                              hipStream_t stream) {
    const float* z     = (const float*)d_in[0];
    const float* betas = (const float*)d_in[1];
    const float* xi    = (const float*)d_in[2];
    const float* mask  = (const float*)d_in[3];
    float* out = (float*)d_out;
    (void)d_ws; (void)ws_size;   // workspace unused (poison fill is unconditional anyway)

    prep_wfrag<<<(WF2_SHORTS + 255) / 256, 256, 0, stream>>>(xi, mask);
    vindy_mfma<<<NROWS / 256, 512, 0, stream>>>(z, betas, out);
}